// Round 9
// baseline (70.168 us; speedup 1.0000x reference)
//
#include <hip/hip_runtime.h>

#define T_LEN  1048576
#define NROWS  32
#define NTAPS  128
#define N2     32
#define BLOCK  256
#define SEG    4096           /* outputs per segment */
#define SPB    8              /* segments per block; grid = 32 rows x 32 blocks */
#define HALO   256            /* staged element e <-> x[sn0 - HALO + e] */
#define NCH    11             /* K chunks of 16: k = m + 129 - 16c - s */
#define STG_F32 (SEG + HALO)  /* 4352 staged elements */
#define STG_Q4  (STG_F32 / 4) /* 1088 float4 loads */
#define EPI_F32 (32 * 36)     /* per-wave epilogue region, pad 36 */
#define XH_BYTES 8704         /* 4352 fp16 */

typedef __attribute__((ext_vector_type(8)))  _Float16 half8;
typedef __attribute__((ext_vector_type(2)))  __fp16   fp16x2;
typedef __attribute__((ext_vector_type(16))) float    f32x16;

__device__ __forceinline__ int swz16(int q) { return q ^ ((q >> 3) & 7); }

// ---- kernel 1: impulse response h[0..127] (+D at 0); fp16 Toeplitz A-frags ----
// A_c[m,s] = h[m + 129 - 16c - s], lane=(m=lane&31, g=lane>>5), s=8g+i
__global__ __launch_bounds__(NTAPS) void ssm_taps(
    const float* __restrict__ w_real, const float* __restrict__ w_imag,
    const float* __restrict__ log_dt,
    const float* __restrict__ C_real, const float* __restrict__ C_imag,
    const float* __restrict__ B_real, const float* __restrict__ B_imag,
    const float* __restrict__ Dp, float* __restrict__ ws) {
  __shared__ float hsh[NTAPS];
  const int k = threadIdx.x;                 // 0..127
  const float dt = expf(log_dt[0]);
  const float kf = (float)k;
  float acc = 0.f;
  for (int n = 0; n < N2; ++n) {
    const float a  = dt * w_real[n];
    const float b  = dt * w_imag[n];
    const float cr = C_real[n], ci = C_imag[n];
    const float br = B_real[n], bi = B_imag[n];
    const float coef_r = cr * br - ci * bi;
    const float coef_i = cr * bi + ci * br;
    const float e = expf(a * kf);
    float s, c;
    sincosf(b * kf, &s, &c);
    acc += e * (coef_r * c - coef_i * s);
  }
  if (k == 0) acc += Dp[0];
  ws[k]  = acc;                              // plain h (exact tail)
  hsh[k] = acc;
  __syncthreads();
  if (k < 64) {
    _Float16* AH = (_Float16*)(ws + NTAPS);
    const int m = k & 31, g = k >> 5;
    for (int c = 0; c < NCH; ++c)
      for (int i = 0; i < 8; ++i) {
        const int idx = m + 129 - 16 * c - 8 * g - i;
        const float v = (idx >= 0 && idx < NTAPS) ? hsh[idx] : 0.f;
        AH[(c * 64 + k) * 8 + i] = (_Float16)v;   // RNE
      }
  }
}

// ---- kernel 2: pipelined implicit-GEMM FIR.  Per block: 8 segments,
//      double-buffered fp16 LDS stage, 2-deep register prefetch (T14 split),
//      one barrier/segment, vector transpose epilogue, merged exact tail ----
__global__ __launch_bounds__(BLOCK, 4) void ssm_conv(
    const float* __restrict__ x, const float* __restrict__ ws,
    float* __restrict__ out) {
  __shared__ __align__(16) unsigned char smem[2 * XH_BYTES + 4 * EPI_F32 * 4];
  _Float16* xh[2] = {(_Float16*)smem, (_Float16*)(smem + XH_BYTES)};
  float* ebase = (float*)(smem + 2 * XH_BYTES);

  const int tid  = threadIdx.x;
  const int lane = tid & 63;
  const int wid  = tid >> 6;
  const int p    = lane & 31, g = lane >> 5;
  const int row  = blockIdx.x >> 5;          // 32 blocks per row
  const int jb   = blockIdx.x & 31;
  const int bb   = jb * (SPB * SEG);         // block base within row
  const float* __restrict__ xrow = x + (size_t)row * T_LEN;

  // A fragments -> VGPRs (L2-hot, coalesced dwordx4)
  half8 A[NCH];
  const half8* __restrict__ wsA = (const half8*)(ws + NTAPS);
#pragma unroll
  for (int c = 0; c < NCH; ++c) A[c] = wsA[c * 64 + lane];

  float4 pf[5];                              // in-flight segment (20 VGPRs)
  auto loadseg = [&](int sn0) {
#pragma unroll
    for (int j = 0; j < 5; ++j) {
      const int q4 = tid + 256 * j;
      if (q4 < STG_Q4) {
        int gfi = sn0 - HALO + 4 * q4;       // clamp left edge (tail re-fixes)
        gfi = gfi < 0 ? 0 : gfi;
        pf[j] = *(const float4*)(xrow + gfi);
      }
    }
  };
  auto cvtwrite = [&](_Float16* dst) {       // compiler inserts the vmcnt wait
#pragma unroll
    for (int j = 0; j < 5; ++j) {
      const int q4 = tid + 256 * j;
      if (q4 < STG_Q4) {
        const fp16x2 a = __builtin_amdgcn_cvt_pkrtz(pf[j].x, pf[j].y);
        const fp16x2 b = __builtin_amdgcn_cvt_pkrtz(pf[j].z, pf[j].w);
        uint2 w;
        w.x = __builtin_bit_cast(unsigned, a);
        w.y = __builtin_bit_cast(unsigned, b);
        const int c16 = q4 >> 1;             // 16B fp16 chunk
        *(uint2*)((char*)dst + swz16(c16) * 16 + (q4 & 1) * 8) = w;
      }
    }
  };

  // prologue: stage seg0, launch seg1 loads
  loadseg(bb);
  cvtwrite(xh[0]);
  loadseg(bb + SEG);
  __syncthreads();

  const int qb = wid * 128 + 4 * p + g;      // lane's fp16-chunk base
#pragma unroll
  for (int s = 0; s < SPB; ++s) {
    const _Float16* xr = xh[s & 1];

    // compute: 11 x { ds_read_b128 + MFMA }; prefetched loads fly underneath
    f32x16 acc = {};
#pragma unroll
    for (int c = 0; c < NCH; ++c) {
      const half8 B = *(const half8*)((const char*)xr + swz16(qb + 2 * c) * 16);
      acc = __builtin_amdgcn_mfma_f32_32x32x16_f16(A[c], B, acc, 0, 0, 0);
    }

    // epilogue: wave-private pad-36 transpose (lgkmcnt-ordered), coalesced stores
    float* ebuf = ebase + wid * EPI_F32;
#pragma unroll
    for (int k = 0; k < 4; ++k) {            // quad r=4k..4k+3: m = 8k+4g+j, col p
      float4 v;
      v.x = acc[4 * k];     v.y = acc[4 * k + 1];
      v.z = acc[4 * k + 2]; v.w = acc[4 * k + 3];
      *(float4*)(ebuf + p * 36 + 8 * k + 4 * g) = v;
    }
    float* __restrict__ obase = out + (size_t)row * T_LEN + bb + s * SEG + wid * 1024;
#pragma unroll
    for (int pp = 0; pp < 4; ++pp) {
      const int o  = 4 * lane + 256 * pp;
      const int m0 = o & 31, pc = o >> 5;
      const float4 v = *(const float4*)(ebuf + pc * 36 + m0);
      *(float4*)(obase + o) = v;
    }

    if (s + 1 < SPB) {
      cvtwrite(xh[(s + 1) & 1]);             // consume in-flight seg s+1
      if (s + 2 < SPB) loadseg(bb + (s + 2) * SEG);   // launch seg s+2
      __syncthreads();                       // xh[(s+1)&1] ready; xr retire-safe
    }
  }

  // merged exact fp32 tail: first block of each row rewrites n in [0,254)
  if (jb == 0) {
    __syncthreads();                         // drains this block's stores (vmcnt 0)
    const float* __restrict__ h = ws;
    if (tid < 254) {
      float a = 0.f;
      if (tid < 127) {                       // circular wraparound region
        for (int k = tid + 1; k < NTAPS; ++k)
          a += h[k] * xrow[T_LEN + tid - k];
      } else {                               // causal with zero left-pad
        for (int k = 0; k <= tid - 127; ++k)
          a += h[k] * xrow[tid - 127 - k];
      }
      out[(size_t)row * T_LEN + tid] = a;
    }
  }
}

extern "C" void kernel_launch(void* const* d_in, const int* in_sizes, int n_in,
                              void* d_out, int out_size, void* d_ws, size_t ws_size,
                              hipStream_t stream) {
  const float* x      = (const float*)d_in[0];
  const float* w_real = (const float*)d_in[1];
  const float* w_imag = (const float*)d_in[2];
  const float* log_dt = (const float*)d_in[3];
  const float* C_real = (const float*)d_in[4];
  const float* C_imag = (const float*)d_in[5];
  const float* B_real = (const float*)d_in[6];
  const float* B_imag = (const float*)d_in[7];
  const float* Dp     = (const float*)d_in[8];
  float* out = (float*)d_out;
  float* ws  = (float*)d_ws;   // 128 f32 h + NCH*64*8 fp16 A-frags = 11.8 KB

  ssm_taps<<<1, NTAPS, 0, stream>>>(w_real, w_imag, log_dt,
                                    C_real, C_imag, B_real, B_imag, Dp, ws);
  ssm_conv<<<NROWS * 32, BLOCK, 0, stream>>>(x, ws, out);
}

// Round 11
// 66.108 us; speedup vs baseline: 1.0614x; 1.0614x over previous
//
#include <hip/hip_runtime.h>

#define T_LEN  1048576
#define NROWS  32
#define NTAPS  128
#define N2     32
#define BLOCK  256
#define SEG    4096           /* outputs per block */
#define SEGS_PER_ROW 256
#define HALO   256            /* staged element e <-> x[n0 - HALO + e] */
#define NCH    11             /* K chunks of 16: k = m + 129 - 16c - s */
#define STG_F32 (SEG + HALO)  /* 4352 staged elements */
#define STG_Q4  (STG_F32 / 4) /* 1088 float4 loads */
#define XH_BYTES 8704         /* 4352 fp16 */
#define SMEM_BYTES (XH_BYTES + 4 * 1024 * 4)   /* + 4 KB epi per wave */

typedef __attribute__((ext_vector_type(8)))  _Float16 half8;
typedef __attribute__((ext_vector_type(2)))  __fp16   fp16x2;
typedef __attribute__((ext_vector_type(16))) float    f32x16;
typedef __attribute__((ext_vector_type(4)))  float    f32x4;

__device__ __forceinline__ int swz16(int q) { return q ^ ((q >> 3) & 7); }

// ---- kernel 1: impulse response h[0..127] (+D at 0); fp16 Toeplitz A-frags ----
// A_c[m,s] = h[m + 129 - 16c - s], lane=(m=lane&31, g=lane>>5), s=8g+i
__global__ __launch_bounds__(NTAPS) void ssm_taps(
    const float* __restrict__ w_real, const float* __restrict__ w_imag,
    const float* __restrict__ log_dt,
    const float* __restrict__ C_real, const float* __restrict__ C_imag,
    const float* __restrict__ B_real, const float* __restrict__ B_imag,
    const float* __restrict__ Dp, float* __restrict__ ws) {
  __shared__ float hsh[NTAPS];
  const int k = threadIdx.x;                 // 0..127
  const float dt = expf(log_dt[0]);
  const float kf = (float)k;
  float acc = 0.f;
  for (int n = 0; n < N2; ++n) {
    const float a  = dt * w_real[n];
    const float b  = dt * w_imag[n];
    const float cr = C_real[n], ci = C_imag[n];
    const float br = B_real[n], bi = B_imag[n];
    const float coef_r = cr * br - ci * bi;
    const float coef_i = cr * bi + ci * br;
    const float e = expf(a * kf);
    float s, c;
    sincosf(b * kf, &s, &c);
    acc += e * (coef_r * c - coef_i * s);
  }
  if (k == 0) acc += Dp[0];
  ws[k]  = acc;                              // plain h (exact tail)
  hsh[k] = acc;
  __syncthreads();
  if (k < 64) {
    _Float16* AH = (_Float16*)(ws + NTAPS);
    const int m = k & 31, g = k >> 5;
    for (int c = 0; c < NCH; ++c)
      for (int i = 0; i < 8; ++i) {
        const int idx = m + 129 - 16 * c - 8 * g - i;
        const float v = (idx >= 0 && idx < NTAPS) ? hsh[idx] : 0.f;
        AH[(c * 64 + k) * 8 + i] = (_Float16)v;   // RNE
      }
  }
}

// ---- kernel 2: one-shot implicit-GEMM FIR; fp16 LDS staging, A in VGPRs,
//      single barrier, conflict-free swizzled-quad epilogue, NT stores ----
__global__ __launch_bounds__(BLOCK, 6) void ssm_conv(
    const float* __restrict__ x, const float* __restrict__ ws,
    float* __restrict__ out) {
  __shared__ __align__(16) unsigned char smem[SMEM_BYTES];
  _Float16* xh    = (_Float16*)smem;
  float*    ebase = (float*)(smem + XH_BYTES);

  const int tid  = threadIdx.x;
  const int lane = tid & 63;
  const int wid  = tid >> 6;
  const int p    = lane & 31, g = lane >> 5;
  const int row  = blockIdx.x >> 8;          // 256 blocks per row
  const int jb   = blockIdx.x & 255;
  const int n0   = jb * SEG;
  const float* __restrict__ xrow = x + (size_t)row * T_LEN;

  // stage x as fp16: coalesced float4 load -> cvt once -> swizzled 8B ds_write
#pragma unroll
  for (int j = 0; j < 5; ++j) {
    const int q4 = tid + 256 * j;            // float4 index
    if (q4 < STG_Q4) {
      int gfi = n0 - HALO + 4 * q4;          // clamp left edge (tail re-fixes)
      gfi = gfi < 0 ? 0 : gfi;
      const float4 f = *(const float4*)(xrow + gfi);
      const fp16x2 a = __builtin_amdgcn_cvt_pkrtz(f.x, f.y);
      const fp16x2 b = __builtin_amdgcn_cvt_pkrtz(f.z, f.w);
      uint2 w;
      w.x = __builtin_bit_cast(unsigned, a);
      w.y = __builtin_bit_cast(unsigned, b);
      const int c16 = q4 >> 1;               // 16B fp16 chunk
      *(uint2*)((char*)xh + swz16(c16) * 16 + (q4 & 1) * 8) = w;
    }
  }

  // A fragments -> VGPRs (L2-hot, coalesced dwordx4)
  half8 A[NCH];
  const half8* __restrict__ wsA = (const half8*)(ws + NTAPS);
#pragma unroll
  for (int c = 0; c < NCH; ++c) A[c] = wsA[c * 64 + lane];

  __syncthreads();                           // the only barrier

  // compute: 11 x { 1 ds_read_b128 + 1 MFMA }
  const int qb = wid * 128 + 4 * p + g;      // lane's fp16-chunk base
  f32x16 acc = {};
#pragma unroll
  for (int c = 0; c < NCH; ++c) {
    const half8 B = *(const half8*)((char*)xh + swz16(qb + 2 * c) * 16);
    acc = __builtin_amdgcn_mfma_f32_32x32x16_f16(A[c], B, acc, 0, 0, 0);
  }

  // epilogue: wave-private transpose on a [32 pc][8 qm] float4-quad grid with
  // XOR swizzle sig(q) = q ^ ((q>>3)&7) -> conflict-free writes AND reads.
  // Write: quad r=4k..4k+3 holds m = 8k+4g+j (col p) -> qm = 2k+g, q = 8p+qm.
  float* ebuf = ebase + wid * 1024;
#pragma unroll
  for (int k = 0; k < 4; ++k) {
    const int q = p * 8 + 2 * k + g;
    float4 v;
    v.x = acc[4 * k];     v.y = acc[4 * k + 1];
    v.z = acc[4 * k + 2]; v.w = acc[4 * k + 3];
    *(float4*)(ebuf + (q ^ (p & 7)) * 4) = v;
  }
  // Read (lgkmcnt-ordered, wave-private): outputs o..o+3, o = 32*pc + 4*qm.
  float* __restrict__ obase = out + (size_t)row * T_LEN + n0 + wid * 1024;
#pragma unroll
  for (int pp = 0; pp < 4; ++pp) {
    const int o  = 4 * lane + 256 * pp;
    const int pc = o >> 5;
    const int q  = pc * 8 + (lane & 7);
    const f32x4 v = *(const f32x4*)(ebuf + (q ^ (pc & 7)) * 4);
    __builtin_nontemporal_store(v, (f32x4*)(obase + o));
  }

  // merged exact fp32 tail: first block of each row rewrites n in [0,254)
  if (jb == 0) {
    __syncthreads();                         // drains this block's stores
    const float* __restrict__ h = ws;
    if (tid < 254) {
      float a = 0.f;
      if (tid < 127) {                       // circular wraparound region
        for (int k = tid + 1; k < NTAPS; ++k)
          a += h[k] * xrow[T_LEN + tid - k];
      } else {                               // causal with zero left-pad
        for (int k = 0; k <= tid - 127; ++k)
          a += h[k] * xrow[tid - 127 - k];
      }
      out[(size_t)row * T_LEN + tid] = a;
    }
  }
}

extern "C" void kernel_launch(void* const* d_in, const int* in_sizes, int n_in,
                              void* d_out, int out_size, void* d_ws, size_t ws_size,
                              hipStream_t stream) {
  const float* x      = (const float*)d_in[0];
  const float* w_real = (const float*)d_in[1];
  const float* w_imag = (const float*)d_in[2];
  const float* log_dt = (const float*)d_in[3];
  const float* C_real = (const float*)d_in[4];
  const float* C_imag = (const float*)d_in[5];
  const float* B_real = (const float*)d_in[6];
  const float* B_imag = (const float*)d_in[7];
  const float* Dp     = (const float*)d_in[8];
  float* out = (float*)d_out;
  float* ws  = (float*)d_ws;   // 128 f32 h + NCH*64*8 fp16 A-frags = 11.8 KB

  ssm_taps<<<1, NTAPS, 0, stream>>>(w_real, w_imag, log_dt,
                                    C_real, C_imag, B_real, B_imag, Dp, ws);
  ssm_conv<<<NROWS * SEGS_PER_ROW, BLOCK, 0, stream>>>(x, ws, out);
}